// Round 2
// baseline (817.365 us; speedup 1.0000x reference)
//
#include <hip/hip_runtime.h>

#define LN_EPS 1e-5f

__device__ __forceinline__ float4 ld4(const float* p) { return *reinterpret_cast<const float4*>(p); }
__device__ __forceinline__ void st4(float* p, float4 v) { *reinterpret_cast<float4*>(p) = v; }

// ---------------- CSR build ----------------

__global__ __launch_bounds__(256) void k_zero_i32(int* __restrict__ p, int n) {
    int i = blockIdx.x * 256 + threadIdx.x;
    if (i < n) p[i] = 0;
}

__global__ __launch_bounds__(256) void k_count(const int* __restrict__ dst, int* __restrict__ counts, int E) {
    int i = blockIdx.x * 256 + threadIdx.x;
    if (i < E) atomicAdd(&counts[dst[i]], 1);
}

__global__ __launch_bounds__(256) void k_dinv(const int* __restrict__ counts, float* __restrict__ dinv, int n) {
    int i = blockIdx.x * 256 + threadIdx.x;
    if (i < n) dinv[i] = rsqrtf((float)(counts[i] + 1));   // +1 = self loop
}

__global__ __launch_bounds__(512) void k_scan1(const int* __restrict__ counts, int* __restrict__ bsum, int n) {
    __shared__ int s[512];
    int idx = blockIdx.x * 512 + threadIdx.x;
    s[threadIdx.x] = (idx < n) ? counts[idx] : 0;
    __syncthreads();
    for (int d = 256; d > 0; d >>= 1) {
        if (threadIdx.x < d) s[threadIdx.x] += s[threadIdx.x + d];
        __syncthreads();
    }
    if (threadIdx.x == 0) bsum[blockIdx.x] = s[0];
}

__global__ void k_scan2(int* __restrict__ bsum, int nb) {
    if (threadIdx.x == 0 && blockIdx.x == 0) {
        int run = 0;
        for (int i = 0; i < nb; ++i) { int t = bsum[i]; bsum[i] = run; run += t; }
    }
}

__global__ __launch_bounds__(512) void k_scan3(const int* __restrict__ counts, const int* __restrict__ bsum,
                                               int* __restrict__ offsets, int* __restrict__ cursor, int n) {
    __shared__ int s[512];
    int tid = threadIdx.x;
    int idx = blockIdx.x * 512 + tid;
    int v = (idx < n) ? counts[idx] : 0;
    s[tid] = v;
    __syncthreads();
    for (int d = 1; d < 512; d <<= 1) {
        int t = (tid >= d) ? s[tid - d] : 0;
        __syncthreads();
        s[tid] += t;
        __syncthreads();
    }
    if (idx < n) {
        int ex = s[tid] - v + bsum[blockIdx.x];
        offsets[idx] = ex;
        cursor[idx] = ex;
    }
}

__global__ __launch_bounds__(256) void k_fill(const int* __restrict__ src, const int* __restrict__ dst,
                                              const float* __restrict__ dinv, int* __restrict__ cursor,
                                              int* __restrict__ csr_src, float* __restrict__ csr_w, int E) {
    int i = blockIdx.x * 256 + threadIdx.x;
    if (i < E) {
        int d = dst[i], s = src[i];
        int p = atomicAdd(&cursor[d], 1);
        csr_src[p] = s;
        csr_w[p] = dinv[s];
    }
}

// ---------------- small-K GEMM: out[N,M] = in[N,K] @ W[K,M] (+bias) ----------------
// W staged in LDS in K-halves of 64; X tile staged in LDS (padded rows).

template <int K, int M>
__global__ __launch_bounds__(256) void gemm_small(const float* __restrict__ in, const float* __restrict__ W,
                                                  const float* __restrict__ bias, float* __restrict__ out,
                                                  int nrows) {
    constexpr int CG = M / 4;         // col groups (float4 per thread)
    constexpr int RG = 256 / CG;      // row groups
    constexpr int RPT = 4;            // rows per thread
    constexpr int ROWS = RG * RPT;    // rows per block-iteration
    constexpr int KH = 64;            // K half staged at a time
    constexpr int KP = K + 4;         // padded X row (keeps float4 alignment, spreads banks)

    __shared__ float Wl[KH][M];
    __shared__ float Xl[ROWS][KP];

    const int tid = threadIdx.x;
    const int cg = tid % CG;
    const int rg = tid / CG;

    float4 bias4 = make_float4(0.f, 0.f, 0.f, 0.f);
    if (bias) bias4 = ld4(bias + cg * 4);

    for (int base = blockIdx.x * ROWS; base < nrows; base += gridDim.x * ROWS) {
        __syncthreads();   // protect Xl/Wl from previous iteration readers
        // stage X tile
        constexpr int NV = ROWS * K / 4;
        for (int i = tid; i < NV; i += 256) {
            int r = i / (K / 4), c = i % (K / 4);
            int gr = base + r;
            float4 v = make_float4(0.f, 0.f, 0.f, 0.f);
            if (gr < nrows) v = ld4(in + (size_t)gr * K + c * 4);
            st4(&Xl[r][c * 4], v);
        }

        float4 acc[RPT];
#pragma unroll
        for (int r = 0; r < RPT; ++r) acc[r] = bias4;

        for (int kh = 0; kh < K; kh += KH) {
            __syncthreads();   // Wl reuse safety (and Xl ready on first pass)
            constexpr int WV = KH * M / 4;
            for (int i = tid; i < WV; i += 256) {
                int kk = i / (M / 4), c = i % (M / 4);
                st4(&Wl[kk][c * 4], ld4(W + (size_t)(kh + kk) * M + c * 4));
            }
            __syncthreads();
#pragma unroll 4
            for (int kk = 0; kk < KH; ++kk) {
                float4 w4 = ld4(&Wl[kk][cg * 4]);
#pragma unroll
                for (int r = 0; r < RPT; ++r) {
                    float xv = Xl[rg * RPT + r][kh + kk];
                    acc[r].x = fmaf(xv, w4.x, acc[r].x);
                    acc[r].y = fmaf(xv, w4.y, acc[r].y);
                    acc[r].z = fmaf(xv, w4.z, acc[r].z);
                    acc[r].w = fmaf(xv, w4.w, acc[r].w);
                }
            }
        }
#pragma unroll
        for (int r = 0; r < RPT; ++r) {
            int gr = base + rg * RPT + r;
            if (gr < nrows) st4(out + (size_t)gr * M + cg * 4, acc[r]);
        }
    }
}

// ---------------- fused conv (H=128) + bias + LayerNorm + ReLU + skip (in place) ----------------
// one 32-lane group per node; lane holds 4 contiguous cols.

__global__ __launch_bounds__(256) void k_conv_ln(const float* __restrict__ hw,
                                                 const int* __restrict__ rs, const int* __restrict__ re,
                                                 const int* __restrict__ csr_src, const float* __restrict__ csr_w,
                                                 const float* __restrict__ dinv,
                                                 const float* __restrict__ bias, const float* __restrict__ g,
                                                 const float* __restrict__ be,
                                                 float* __restrict__ xio, int n) {
    const int grp = threadIdx.x >> 5;
    const int sub = threadIdx.x & 31;
    const int node = blockIdx.x * 8 + grp;
    if (node >= n) return;
    const int c0 = sub * 4;
    const float di = dinv[node];

    float ax = 0.f, ay = 0.f, az = 0.f, aw = 0.f;
    const int p0 = rs[node], p1 = re[node];
    for (int p = p0; p < p1; ++p) {
        int s = csr_src[p];
        float w = csr_w[p] * di;
        float4 v = ld4(hw + (size_t)s * 128 + c0);
        ax = fmaf(v.x, w, ax); ay = fmaf(v.y, w, ay);
        az = fmaf(v.z, w, az); aw = fmaf(v.w, w, aw);
    }
    {   // self loop
        float w = di * di;
        float4 v = ld4(hw + (size_t)node * 128 + c0);
        ax = fmaf(v.x, w, ax); ay = fmaf(v.y, w, ay);
        az = fmaf(v.z, w, az); aw = fmaf(v.w, w, aw);
    }
    {   // bias (pre-LN, as in reference)
        float4 b4 = ld4(bias + c0);
        ax += b4.x; ay += b4.y; az += b4.z; aw += b4.w;
    }
    // LayerNorm over 128 cols (32 lanes x 4)
    float sum = ax + ay + az + aw;
#pragma unroll
    for (int m = 16; m > 0; m >>= 1) sum += __shfl_xor(sum, m, 32);
    const float mean = sum * (1.f / 128.f);
    float dx = ax - mean, dy = ay - mean, dz = az - mean, dw = aw - mean;
    float sq = dx * dx + dy * dy + dz * dz + dw * dw;
#pragma unroll
    for (int m = 16; m > 0; m >>= 1) sq += __shfl_xor(sq, m, 32);
    const float rstd = rsqrtf(sq * (1.f / 128.f) + LN_EPS);
    float4 g4 = ld4(g + c0), be4 = ld4(be + c0);
    float yx = fmaxf(fmaf(dx * rstd, g4.x, be4.x), 0.f);
    float yy = fmaxf(fmaf(dy * rstd, g4.y, be4.y), 0.f);
    float yz = fmaxf(fmaf(dz * rstd, g4.z, be4.z), 0.f);
    float yw = fmaxf(fmaf(dw * rstd, g4.w, be4.w), 0.f);
    float* io = xio + (size_t)node * 128 + c0;
    float4 sk = ld4(io);
    st4(io, make_float4(yx + sk.x, yy + sk.y, yz + sk.z, yw + sk.w));
}

// ---------------- final conv (DOUT=64): d_out += segsum + b3 (d_out pre-filled with skip) ----------------

__global__ __launch_bounds__(256) void k_conv_final(const float* __restrict__ hw,
                                                    const int* __restrict__ rs, const int* __restrict__ re,
                                                    const int* __restrict__ csr_src, const float* __restrict__ csr_w,
                                                    const float* __restrict__ dinv, const float* __restrict__ bias,
                                                    float* __restrict__ out, int n) {
    const int grp = threadIdx.x >> 4;
    const int sub = threadIdx.x & 15;
    const int node = blockIdx.x * 16 + grp;
    if (node >= n) return;
    const int c0 = sub * 4;
    const float di = dinv[node];

    float ax = 0.f, ay = 0.f, az = 0.f, aw = 0.f;
    const int p0 = rs[node], p1 = re[node];
    for (int p = p0; p < p1; ++p) {
        int s = csr_src[p];
        float w = csr_w[p] * di;
        float4 v = ld4(hw + (size_t)s * 64 + c0);
        ax = fmaf(v.x, w, ax); ay = fmaf(v.y, w, ay);
        az = fmaf(v.z, w, az); aw = fmaf(v.w, w, aw);
    }
    {
        float w = di * di;
        float4 v = ld4(hw + (size_t)node * 64 + c0);
        ax = fmaf(v.x, w, ax); ay = fmaf(v.y, w, ay);
        az = fmaf(v.z, w, az); aw = fmaf(v.w, w, aw);
    }
    float4 b4 = ld4(bias + c0);
    float* o = out + (size_t)node * 64 + c0;
    float4 cur = ld4(o);
    st4(o, make_float4(cur.x + ax + b4.x, cur.y + ay + b4.y,
                       cur.z + az + b4.z, cur.w + aw + b4.w));
}

// ---------------- launch ----------------

extern "C" void kernel_launch(void* const* d_in, const int* in_sizes, int n_in,
                              void* d_out, int out_size, void* d_ws, size_t ws_size,
                              hipStream_t stream) {
    const float* x   = (const float*)d_in[0];
    const int* eidx  = (const int*)d_in[1];
    const float* W1  = (const float*)d_in[2];
    const float* b1  = (const float*)d_in[3];
    const float* W2  = (const float*)d_in[4];
    const float* b2  = (const float*)d_in[5];
    const float* W3  = (const float*)d_in[6];
    const float* b3  = (const float*)d_in[7];
    const float* g1  = (const float*)d_in[8];
    const float* be1 = (const float*)d_in[9];
    const float* g2  = (const float*)d_in[10];
    const float* be2 = (const float*)d_in[11];
    const float* Ws1 = (const float*)d_in[12];
    const float* bs1 = (const float*)d_in[13];
    const float* Ws2 = (const float*)d_in[14];
    const float* bs2 = (const float*)d_in[15];
    float* out = (float*)d_out;

    const int N = in_sizes[0] / 64;
    const int E = in_sizes[1] / 2;
    const int* esrc = eidx;
    const int* edst = eidx + E;

    char* p = (char*)d_ws;
    auto alloc = [&](size_t bytes) -> char* {
        char* q = p;
        p += (bytes + 255) & ~(size_t)255;
        return q;
    };
    float* A      = (float*)alloc((size_t)N * 128 * 4);  // h@W products
    float* B      = (float*)alloc((size_t)N * 128 * 4);  // skip1 -> x1 -> x2 (in place)
    int* csr_src  = (int*)alloc((size_t)E * 4);
    float* csr_w  = (float*)alloc((size_t)E * 4);
    int* counts   = (int*)alloc((size_t)N * 4);
    int* offsets  = (int*)alloc((size_t)N * 4);
    int* cursor   = (int*)alloc((size_t)N * 4);
    float* dinv   = (float*)alloc((size_t)N * 4);
    const int NB = (N + 511) / 512;
    int* bsum     = (int*)alloc((size_t)NB * 4);

    const int gN256 = (N + 255) / 256;
    const int gE256 = (E + 255) / 256;

    // ---- CSR build ----
    k_zero_i32<<<gN256, 256, 0, stream>>>(counts, N);
    k_count<<<gE256, 256, 0, stream>>>(edst, counts, E);
    k_dinv<<<gN256, 256, 0, stream>>>(counts, dinv, N);
    k_scan1<<<NB, 512, 0, stream>>>(counts, bsum, N);
    k_scan2<<<1, 64, 0, stream>>>(bsum, NB);
    k_scan3<<<NB, 512, 0, stream>>>(counts, bsum, offsets, cursor, N);
    k_fill<<<gE256, 256, 0, stream>>>(esrc, edst, dinv, cursor, csr_src, csr_w, E);
    // cursor[i] is now row end

    // ---- layer 1 ----
    gemm_small<64, 128><<<(N + 31) / 32, 256, 0, stream>>>(x, W1, nullptr, A, N);    // hw1
    gemm_small<64, 128><<<(N + 31) / 32, 256, 0, stream>>>(x, Ws1, bs1, B, N);       // skip1
    k_conv_ln<<<(N + 7) / 8, 256, 0, stream>>>(A, offsets, cursor, csr_src, csr_w, dinv,
                                               b1, g1, be1, B, N);                   // B = x1

    // ---- layer 2 + skip3 (must read x1 before conv2 overwrites B) ----
    gemm_small<128, 128><<<(N + 31) / 32, 256, 0, stream>>>(B, W2, nullptr, A, N);   // hw2
    gemm_small<128, 64><<<(N + 63) / 64, 256, 0, stream>>>(B, Ws2, bs2, out, N);     // skip3 -> d_out
    k_conv_ln<<<(N + 7) / 8, 256, 0, stream>>>(A, offsets, cursor, csr_src, csr_w, dinv,
                                               b2, g2, be2, B, N);                   // B = x2

    // ---- layer 3 ----
    gemm_small<128, 64><<<(N + 63) / 64, 256, 0, stream>>>(B, W3, nullptr, A, N);    // hw3
    k_conv_final<<<(N + 15) / 16, 256, 0, stream>>>(A, offsets, cursor, csr_src, csr_w,
                                                    dinv, b3, out, N);
}

// Round 3
// 623.570 us; speedup vs baseline: 1.3108x; 1.3108x over previous
//
#include <hip/hip_runtime.h>

#define LN_EPS 1e-5f

typedef unsigned short ushortT;

__device__ __forceinline__ float4 ld4(const float* p) { return *reinterpret_cast<const float4*>(p); }
__device__ __forceinline__ void st4(float* p, float4 v) { *reinterpret_cast<float4*>(p) = v; }
__device__ __forceinline__ float bf2f(unsigned u) { return __uint_as_float(u << 16); }
__device__ __forceinline__ unsigned short f2bf(float f) {
    unsigned u = __float_as_uint(f);
    u += 0x7fffu + ((u >> 16) & 1u);   // round to nearest even
    return (unsigned short)(u >> 16);
}
__device__ __forceinline__ unsigned pack2(float a, float b) {
    return (unsigned)f2bf(a) | ((unsigned)f2bf(b) << 16);
}

// ---------------- CSR build ----------------

__global__ __launch_bounds__(256) void k_zero_i32(int* __restrict__ p, int n) {
    int i = blockIdx.x * 256 + threadIdx.x;
    if (i < n) p[i] = 0;
}

__global__ __launch_bounds__(256) void k_count(const int* __restrict__ dst, int* __restrict__ counts, int E) {
    int i = blockIdx.x * 256 + threadIdx.x;
    if (i < E) atomicAdd(&counts[dst[i]], 1);
}

__global__ __launch_bounds__(256) void k_dinv(const int* __restrict__ counts, float* __restrict__ dinv, int n) {
    int i = blockIdx.x * 256 + threadIdx.x;
    if (i < n) dinv[i] = rsqrtf((float)(counts[i] + 1));   // +1 = self loop
}

__global__ __launch_bounds__(512) void k_scan1(const int* __restrict__ counts, int* __restrict__ bsum, int n) {
    __shared__ int s[512];
    int idx = blockIdx.x * 512 + threadIdx.x;
    s[threadIdx.x] = (idx < n) ? counts[idx] : 0;
    __syncthreads();
    for (int d = 256; d > 0; d >>= 1) {
        if (threadIdx.x < d) s[threadIdx.x] += s[threadIdx.x + d];
        __syncthreads();
    }
    if (threadIdx.x == 0) bsum[blockIdx.x] = s[0];
}

// parallel single-block exclusive scan over block sums (nb <= 512)
__global__ __launch_bounds__(512) void k_scan2(int* __restrict__ bsum, int nb) {
    __shared__ int s[512];
    int t = threadIdx.x;
    int v = (t < nb) ? bsum[t] : 0;
    s[t] = v;
    __syncthreads();
    for (int d = 1; d < 512; d <<= 1) {
        int tv = (t >= d) ? s[t - d] : 0;
        __syncthreads();
        s[t] += tv;
        __syncthreads();
    }
    if (t < nb) bsum[t] = s[t] - v;   // exclusive
}

__global__ __launch_bounds__(512) void k_scan3(const int* __restrict__ counts, const int* __restrict__ bsum,
                                               int* __restrict__ offsets, int* __restrict__ cursor, int n) {
    __shared__ int s[512];
    int tid = threadIdx.x;
    int idx = blockIdx.x * 512 + tid;
    int v = (idx < n) ? counts[idx] : 0;
    s[tid] = v;
    __syncthreads();
    for (int d = 1; d < 512; d <<= 1) {
        int t = (tid >= d) ? s[tid - d] : 0;
        __syncthreads();
        s[tid] += t;
        __syncthreads();
    }
    if (idx < n) {
        int ex = s[tid] - v + bsum[blockIdx.x];
        offsets[idx] = ex;
        cursor[idx] = ex;
    }
}

__global__ __launch_bounds__(256) void k_fill(const int* __restrict__ src, const int* __restrict__ dst,
                                              const float* __restrict__ dinv, int* __restrict__ cursor,
                                              int* __restrict__ csr_src, float* __restrict__ csr_w, int E) {
    int i = blockIdx.x * 256 + threadIdx.x;
    if (i < E) {
        int d = dst[i], s = src[i];
        int p = atomicAdd(&cursor[d], 1);
        csr_src[p] = s;
        csr_w[p] = dinv[s];
    }
}

// ---------------- f32 -> bf16 convert ----------------

__global__ __launch_bounds__(256) void k_cvt_bf16(const float* __restrict__ in, ushortT* __restrict__ o, int n4) {
    int i = blockIdx.x * 256 + threadIdx.x;
    if (i < n4) {
        float4 v = ld4(in + (size_t)i * 4);
        uint2 pk;
        pk.x = pack2(v.x, v.y);
        pk.y = pack2(v.z, v.w);
        *reinterpret_cast<uint2*>(o + (size_t)i * 4) = pk;
    }
}

// ---------------- aggregation: agg[node] = sum_{s in N(node)} w * t16[s] + dinv^2 * t16[node] ----------------
// bf16 table rows, 16B (8 bf16) per lane; G = C/8 lanes per node.

template <int C>
__global__ __launch_bounds__(256) void k_agg(const ushortT* __restrict__ t16,
                                             const int* __restrict__ rs, const int* __restrict__ re,
                                             const int* __restrict__ csr_src, const float* __restrict__ csr_w,
                                             const float* __restrict__ dinv, float* __restrict__ agg, int n) {
    constexpr int G = C / 8;
    constexpr int NPB = 256 / G;
    const int grp = threadIdx.x / G;
    const int sub = threadIdx.x % G;
    const int node = blockIdx.x * NPB + grp;
    if (node >= n) return;
    const float di = dinv[node];
    float a[8];
#pragma unroll
    for (int i = 0; i < 8; ++i) a[i] = 0.f;
    const ushortT* base = t16 + sub * 8;
    const int p0 = rs[node], p1 = re[node];

    auto acc8 = [&](uint4 v, float w) {
        a[0] = fmaf(bf2f(v.x & 0xffffu), w, a[0]); a[1] = fmaf(bf2f(v.x >> 16), w, a[1]);
        a[2] = fmaf(bf2f(v.y & 0xffffu), w, a[2]); a[3] = fmaf(bf2f(v.y >> 16), w, a[3]);
        a[4] = fmaf(bf2f(v.z & 0xffffu), w, a[4]); a[5] = fmaf(bf2f(v.z >> 16), w, a[5]);
        a[6] = fmaf(bf2f(v.w & 0xffffu), w, a[6]); a[7] = fmaf(bf2f(v.w >> 16), w, a[7]);
    };

    int p = p0;
    for (; p + 2 <= p1; p += 2) {
        int s0 = csr_src[p], s1 = csr_src[p + 1];
        float w0 = csr_w[p] * di, w1 = csr_w[p + 1] * di;
        uint4 v0 = *reinterpret_cast<const uint4*>(base + (size_t)s0 * C);
        uint4 v1 = *reinterpret_cast<const uint4*>(base + (size_t)s1 * C);
        acc8(v0, w0);
        acc8(v1, w1);
    }
    if (p < p1) {
        int s0 = csr_src[p];
        float w0 = csr_w[p] * di;
        uint4 v0 = *reinterpret_cast<const uint4*>(base + (size_t)s0 * C);
        acc8(v0, w0);
    }
    {   // self loop
        uint4 v = *reinterpret_cast<const uint4*>(base + (size_t)node * C);
        acc8(v, di * di);
    }
    float* o = agg + (size_t)node * C + sub * 8;
    st4(o, make_float4(a[0], a[1], a[2], a[3]));
    st4(o + 4, make_float4(a[4], a[5], a[6], a[7]));
}

// ---------------- final: out += Agg(hw3_16) + b3 (out pre-filled with skip3) ----------------

__global__ __launch_bounds__(256) void k_final(const ushortT* __restrict__ t16,
                                               const int* __restrict__ rs, const int* __restrict__ re,
                                               const int* __restrict__ csr_src, const float* __restrict__ csr_w,
                                               const float* __restrict__ dinv, const float* __restrict__ bias,
                                               float* __restrict__ out, int n) {
    constexpr int C = 64, G = 8, NPB = 32;
    const int grp = threadIdx.x / G;
    const int sub = threadIdx.x % G;
    const int node = blockIdx.x * NPB + grp;
    if (node >= n) return;
    const float di = dinv[node];
    float a[8];
#pragma unroll
    for (int i = 0; i < 8; ++i) a[i] = 0.f;
    const ushortT* base = t16 + sub * 8;
    const int p0 = rs[node], p1 = re[node];

    auto acc8 = [&](uint4 v, float w) {
        a[0] = fmaf(bf2f(v.x & 0xffffu), w, a[0]); a[1] = fmaf(bf2f(v.x >> 16), w, a[1]);
        a[2] = fmaf(bf2f(v.y & 0xffffu), w, a[2]); a[3] = fmaf(bf2f(v.y >> 16), w, a[3]);
        a[4] = fmaf(bf2f(v.z & 0xffffu), w, a[4]); a[5] = fmaf(bf2f(v.z >> 16), w, a[5]);
        a[6] = fmaf(bf2f(v.w & 0xffffu), w, a[6]); a[7] = fmaf(bf2f(v.w >> 16), w, a[7]);
    };

    int p = p0;
    for (; p + 2 <= p1; p += 2) {
        int s0 = csr_src[p], s1 = csr_src[p + 1];
        float w0 = csr_w[p] * di, w1 = csr_w[p + 1] * di;
        uint4 v0 = *reinterpret_cast<const uint4*>(base + (size_t)s0 * C);
        uint4 v1 = *reinterpret_cast<const uint4*>(base + (size_t)s1 * C);
        acc8(v0, w0);
        acc8(v1, w1);
    }
    if (p < p1) {
        int s0 = csr_src[p];
        float w0 = csr_w[p] * di;
        uint4 v0 = *reinterpret_cast<const uint4*>(base + (size_t)s0 * C);
        acc8(v0, w0);
    }
    {
        uint4 v = *reinterpret_cast<const uint4*>(base + (size_t)node * C);
        acc8(v, di * di);
    }
    float* o = out + (size_t)node * 64 + sub * 8;
    const float* b = bias + sub * 8;
    float4 c0 = ld4(o), c1 = ld4(o + 4);
    float4 b0 = ld4(b), b1 = ld4(b + 4);
    st4(o, make_float4(c0.x + a[0] + b0.x, c0.y + a[1] + b0.y,
                       c0.z + a[2] + b0.z, c0.w + a[3] + b0.w));
    st4(o + 4, make_float4(c1.x + a[4] + b1.x, c1.y + a[5] + b1.y,
                           c1.z + a[6] + b1.z, c1.w + a[7] + b1.w));
}

// ---------------- small-K GEMM: out[N,M] = in[N,K] @ W[K,M] (+bias); f32 or bf16 out ----------------

template <int K, int M, bool BF16OUT>
__global__ __launch_bounds__(256) void gemm_small(const float* __restrict__ in, const float* __restrict__ W,
                                                  const float* __restrict__ bias, void* __restrict__ outp,
                                                  int nrows) {
    constexpr int CG = M / 4;
    constexpr int RG = 256 / CG;
    constexpr int RPT = 4;
    constexpr int ROWS = RG * RPT;
    constexpr int KH = 64;
    constexpr int KP = K + 4;

    __shared__ float Wl[KH][M];
    __shared__ float Xl[ROWS][KP];

    const int tid = threadIdx.x;
    const int cg = tid % CG;
    const int rg = tid / CG;

    float4 bias4 = make_float4(0.f, 0.f, 0.f, 0.f);
    if (bias) bias4 = ld4(bias + cg * 4);

    for (int base = blockIdx.x * ROWS; base < nrows; base += gridDim.x * ROWS) {
        __syncthreads();
        constexpr int NV = ROWS * K / 4;
        for (int i = tid; i < NV; i += 256) {
            int r = i / (K / 4), c = i % (K / 4);
            int gr = base + r;
            float4 v = make_float4(0.f, 0.f, 0.f, 0.f);
            if (gr < nrows) v = ld4(in + (size_t)gr * K + c * 4);
            st4(&Xl[r][c * 4], v);
        }

        float4 acc[RPT];
#pragma unroll
        for (int r = 0; r < RPT; ++r) acc[r] = bias4;

        for (int kh = 0; kh < K; kh += KH) {
            __syncthreads();
            constexpr int WV = KH * M / 4;
            for (int i = tid; i < WV; i += 256) {
                int kk = i / (M / 4), c = i % (M / 4);
                st4(&Wl[kk][c * 4], ld4(W + (size_t)(kh + kk) * M + c * 4));
            }
            __syncthreads();
#pragma unroll 4
            for (int kk = 0; kk < KH; ++kk) {
                float4 w4 = ld4(&Wl[kk][cg * 4]);
#pragma unroll
                for (int r = 0; r < RPT; ++r) {
                    float xv = Xl[rg * RPT + r][kh + kk];
                    acc[r].x = fmaf(xv, w4.x, acc[r].x);
                    acc[r].y = fmaf(xv, w4.y, acc[r].y);
                    acc[r].z = fmaf(xv, w4.z, acc[r].z);
                    acc[r].w = fmaf(xv, w4.w, acc[r].w);
                }
            }
        }
#pragma unroll
        for (int r = 0; r < RPT; ++r) {
            int gr = base + rg * RPT + r;
            if (gr < nrows) {
                if (BF16OUT) {
                    uint2 pk;
                    pk.x = pack2(acc[r].x, acc[r].y);
                    pk.y = pack2(acc[r].z, acc[r].w);
                    *reinterpret_cast<uint2*>((ushortT*)outp + (size_t)gr * M + cg * 4) = pk;
                } else {
                    st4((float*)outp + (size_t)gr * M + cg * 4, acc[r]);
                }
            }
        }
    }
}

// ---------------- GEMM + bias + LayerNorm + ReLU + skip, f32 out + optional bf16 out (M=128) ----------------

template <int K>
__global__ __launch_bounds__(256) void gemm_ln(const float* __restrict__ in, const float* __restrict__ W,
                                               const float* __restrict__ bias, const float* __restrict__ g,
                                               const float* __restrict__ be, const float* __restrict__ skip,
                                               float* __restrict__ out32, ushortT* __restrict__ out16,
                                               int nrows) {
    constexpr int M = 128;
    constexpr int RPT = 4;
    constexpr int ROWS = 32;          // (256/32)*4
    constexpr int KH = 64;
    constexpr int KP = K + 4;

    __shared__ float Wl[KH][M];
    __shared__ float Xl[ROWS][KP];

    const int tid = threadIdx.x;
    const int cg = tid & 31;
    const int rg = tid >> 5;

    const float4 bias4 = ld4(bias + cg * 4);
    const float4 g4 = ld4(g + cg * 4);
    const float4 be4 = ld4(be + cg * 4);

    for (int base = blockIdx.x * ROWS; base < nrows; base += gridDim.x * ROWS) {
        __syncthreads();
        constexpr int NV = ROWS * K / 4;
        for (int i = tid; i < NV; i += 256) {
            int r = i / (K / 4), c = i % (K / 4);
            int gr = base + r;
            float4 v = make_float4(0.f, 0.f, 0.f, 0.f);
            if (gr < nrows) v = ld4(in + (size_t)gr * K + c * 4);
            st4(&Xl[r][c * 4], v);
        }

        float4 acc[RPT];
#pragma unroll
        for (int r = 0; r < RPT; ++r) acc[r] = bias4;

        for (int kh = 0; kh < K; kh += KH) {
            __syncthreads();
            constexpr int WV = KH * M / 4;
            for (int i = tid; i < WV; i += 256) {
                int kk = i / (M / 4), c = i % (M / 4);
                st4(&Wl[kk][c * 4], ld4(W + (size_t)(kh + kk) * M + c * 4));
            }
            __syncthreads();
#pragma unroll 4
            for (int kk = 0; kk < KH; ++kk) {
                float4 w4 = ld4(&Wl[kk][cg * 4]);
#pragma unroll
                for (int r = 0; r < RPT; ++r) {
                    float xv = Xl[rg * RPT + r][kh + kk];
                    acc[r].x = fmaf(xv, w4.x, acc[r].x);
                    acc[r].y = fmaf(xv, w4.y, acc[r].y);
                    acc[r].z = fmaf(xv, w4.z, acc[r].z);
                    acc[r].w = fmaf(xv, w4.w, acc[r].w);
                }
            }
        }

        // epilogue: LN(row of 128 spread over 32 lanes) + relu + skip
#pragma unroll
        for (int r = 0; r < RPT; ++r) {
            int gr = base + rg * RPT + r;
            if (gr >= nrows) continue;
            float4 a = acc[r];
            float sum = a.x + a.y + a.z + a.w;
#pragma unroll
            for (int m = 16; m > 0; m >>= 1) sum += __shfl_xor(sum, m, 32);
            const float mean = sum * (1.f / 128.f);
            float dx = a.x - mean, dy = a.y - mean, dz = a.z - mean, dw = a.w - mean;
            float sq = dx * dx + dy * dy + dz * dz + dw * dw;
#pragma unroll
            for (int m = 16; m > 0; m >>= 1) sq += __shfl_xor(sq, m, 32);
            const float rstd = rsqrtf(sq * (1.f / 128.f) + LN_EPS);
            float4 s4 = ld4(skip + (size_t)gr * 128 + cg * 4);
            float4 y;
            y.x = fmaxf(fmaf(dx * rstd, g4.x, be4.x), 0.f) + s4.x;
            y.y = fmaxf(fmaf(dy * rstd, g4.y, be4.y), 0.f) + s4.y;
            y.z = fmaxf(fmaf(dz * rstd, g4.z, be4.z), 0.f) + s4.z;
            y.w = fmaxf(fmaf(dw * rstd, g4.w, be4.w), 0.f) + s4.w;
            st4(out32 + (size_t)gr * 128 + cg * 4, y);
            if (out16) {
                uint2 pk;
                pk.x = pack2(y.x, y.y);
                pk.y = pack2(y.z, y.w);
                *reinterpret_cast<uint2*>(out16 + (size_t)gr * 128 + cg * 4) = pk;
            }
        }
    }
}

// ---------------- launch ----------------

extern "C" void kernel_launch(void* const* d_in, const int* in_sizes, int n_in,
                              void* d_out, int out_size, void* d_ws, size_t ws_size,
                              hipStream_t stream) {
    const float* x   = (const float*)d_in[0];
    const int* eidx  = (const int*)d_in[1];
    const float* W1  = (const float*)d_in[2];
    const float* b1  = (const float*)d_in[3];
    const float* W2  = (const float*)d_in[4];
    const float* b2  = (const float*)d_in[5];
    const float* W3  = (const float*)d_in[6];
    const float* b3  = (const float*)d_in[7];
    const float* g1  = (const float*)d_in[8];
    const float* be1 = (const float*)d_in[9];
    const float* g2  = (const float*)d_in[10];
    const float* be2 = (const float*)d_in[11];
    const float* Ws1 = (const float*)d_in[12];
    const float* bs1 = (const float*)d_in[13];
    const float* Ws2 = (const float*)d_in[14];
    const float* bs2 = (const float*)d_in[15];
    float* out = (float*)d_out;

    const int N = in_sizes[0] / 64;
    const int E = in_sizes[1] / 2;
    const int* esrc = eidx;
    const int* edst = eidx + E;

    char* p = (char*)d_ws;
    auto alloc = [&](size_t bytes) -> char* {
        char* q = p;
        p += (bytes + 255) & ~(size_t)255;
        return q;
    };
    // R1: S (skip1) then X2
    float* S      = (float*)alloc((size_t)N * 128 * 4);
    float* X2     = S;
    // R2: X1
    float* X1     = (float*)alloc((size_t)N * 128 * 4);
    // R3: x16 + agg0 packed; later agg1 overwrites
    char* R3      = alloc((size_t)N * 128 * 4);
    ushortT* x16  = (ushortT*)R3;
    float* agg0   = (float*)(R3 + (((size_t)N * 64 * 2 + 255) & ~(size_t)255));
    float* agg1   = (float*)R3;
    // bf16 copies
    ushortT* X1_16  = (ushortT*)alloc((size_t)N * 128 * 2);
    ushortT* HW3_16 = (ushortT*)alloc((size_t)N * 64 * 2);
    // CSR
    int* csr_src  = (int*)alloc((size_t)E * 4);
    float* csr_w  = (float*)alloc((size_t)E * 4);
    int* counts   = (int*)alloc((size_t)N * 4);
    int* offsets  = (int*)alloc((size_t)N * 4);
    int* cursor   = (int*)alloc((size_t)N * 4);
    float* dinv   = (float*)alloc((size_t)N * 4);
    const int NB = (N + 511) / 512;
    int* bsum     = (int*)alloc((size_t)NB * 4);

    const int gN256 = (N + 255) / 256;
    const int gE256 = (E + 255) / 256;

    // ---- CSR build ----
    k_zero_i32<<<gN256, 256, 0, stream>>>(counts, N);
    k_count<<<gE256, 256, 0, stream>>>(edst, counts, E);
    k_dinv<<<gN256, 256, 0, stream>>>(counts, dinv, N);
    k_scan1<<<NB, 512, 0, stream>>>(counts, bsum, N);
    k_scan2<<<1, 512, 0, stream>>>(bsum, NB);
    k_scan3<<<NB, 512, 0, stream>>>(counts, bsum, offsets, cursor, N);
    k_fill<<<gE256, 256, 0, stream>>>(esrc, edst, dinv, cursor, csr_src, csr_w, E);
    // cursor[i] = row end

    // ---- layer 1 (aggregate-first) ----
    k_cvt_bf16<<<(N * 16 + 255) / 256, 256, 0, stream>>>(x, x16, N * 16);            // x -> bf16
    k_agg<64><<<(N + 31) / 32, 256, 0, stream>>>(x16, offsets, cursor, csr_src, csr_w,
                                                 dinv, agg0, N);                     // agg0 = A~ x
    gemm_small<64, 128, false><<<(N + 31) / 32, 256, 0, stream>>>(x, Ws1, bs1, S, N); // skip1
    gemm_ln<64><<<(N + 31) / 32, 256, 0, stream>>>(agg0, W1, b1, g1, be1, S,
                                                   X1, X1_16, N);                    // X1 = x1 (+bf16)

    // ---- layer 2 (aggregate-first) ----
    k_agg<128><<<(N + 15) / 16, 256, 0, stream>>>(X1_16, offsets, cursor, csr_src, csr_w,
                                                  dinv, agg1, N);                    // agg1 = A~ x1
    gemm_ln<128><<<(N + 31) / 32, 256, 0, stream>>>(agg1, W2, b2, g2, be2, X1,
                                                    X2, (ushortT*)nullptr, N);       // X2 = x2

    // ---- layer 3 (gather-last) ----
    gemm_small<128, 64, false><<<(N + 63) / 64, 256, 0, stream>>>(X1, Ws2, bs2, out, N); // skip3 -> out
    gemm_small<128, 64, true><<<(N + 63) / 64, 256, 0, stream>>>(X2, W3, nullptr, HW3_16, N); // hw3 bf16
    k_final<<<(N + 31) / 32, 256, 0, stream>>>(HW3_16, offsets, cursor, csr_src, csr_w,
                                               dinv, b3, out, N);                    // out += A~ hw3 + b3
}